// Round 1
// baseline (341.494 us; speedup 1.0000x reference)
//
#include <hip/hip_runtime.h>
#include <hip/hip_bf16.h>

// Problem: B=2, S=2048, D=1024, H=16, HD=64
// out[i] = rg*(softmax(QK^T/8, causal) @ V)[i] + sg*V[i] - cg*prefixsum(V)[i]/(i+1), then @cproj_w

typedef __hip_bfloat16 bf16;
typedef short s16x8 __attribute__((ext_vector_type(8)));
typedef float f32x4 __attribute__((ext_vector_type(4)));

#define NB 2
#define NS 2048
#define ND 1024
#define NH 16
#define NHD 64

// ---------------- f32 -> bf16 conversion (vectorized) ----------------
__global__ __launch_bounds__(256) void cvt_bf16(const float* __restrict__ in,
                                                bf16* __restrict__ out, int n4) {
  int i = blockIdx.x * 256 + threadIdx.x;
  if (i >= n4) return;
  float4 v = ((const float4*)in)[i];
  ushort4 o;
  bf16 t;
  t = __float2bfloat16(v.x); __builtin_memcpy(&o.x, &t, 2);
  t = __float2bfloat16(v.y); __builtin_memcpy(&o.y, &t, 2);
  t = __float2bfloat16(v.z); __builtin_memcpy(&o.z, &t, 2);
  t = __float2bfloat16(v.w); __builtin_memcpy(&o.w, &t, 2);
  ((ushort4*)out)[i] = o;
}

// ------------- transpose + convert: in[K,N] f32 -> out[N,K] bf16 -------------
__global__ __launch_bounds__(256) void tconv(const float* __restrict__ in,
                                             bf16* __restrict__ out, int K, int N) {
  __shared__ float tile[32][33];
  int nt = blockIdx.x * 32, kt = blockIdx.y * 32;
  int tx = threadIdx.x, ty = threadIdx.y;  // block (32,8)
#pragma unroll
  for (int j = 0; j < 32; j += 8)
    tile[ty + j][tx] = in[(size_t)(kt + ty + j) * N + nt + tx];
  __syncthreads();
#pragma unroll
  for (int j = 0; j < 32; j += 8)
    out[(size_t)(nt + ty + j) * K + kt + tx] = __float2bfloat16(tile[tx][ty + j]);
}

// ---------------- 128x128x32 bf16 MFMA GEMM, B^T input ----------------
// MODE 0: C = A@B + bias -> split cols [0,1024)->q, [1024,2048)->k, head-major bf16
// MODE 1: C = A@B -> v head-major bf16
// MODE 2: C = A@B -> f32 row-major (d_out)
template <int MODE>
__global__ __launch_bounds__(256) void gemm_bt(const bf16* __restrict__ A,
                                               const bf16* __restrict__ Bt,
                                               const float* __restrict__ bias,
                                               bf16* __restrict__ o0, bf16* __restrict__ o1,
                                               float* __restrict__ of,
                                               int M, int N, int K) {
  __shared__ alignas(16) bf16 As[128 * 32];
  __shared__ alignas(16) bf16 Bs[128 * 32];
  const int tid = threadIdx.x;
  const int wave = tid >> 6, lane = tid & 63;
  const int l15 = lane & 15, lg = lane >> 4;
  const int wr = wave >> 1, wc = wave & 1;
  const int brow = blockIdx.y * 128, bcol = blockIdx.x * 128;

  f32x4 acc[4][4] = {};
  const int arow = tid >> 2;        // 0..63
  const int ak = (tid & 3) * 8;     // 0,8,16,24

  for (int k0 = 0; k0 < K; k0 += 32) {
#pragma unroll
    for (int c = 0; c < 2; ++c) {
      int r = arow + c * 64;
      *(s16x8*)(As + r * 32 + ak) = *(const s16x8*)(A + (size_t)(brow + r) * K + k0 + ak);
      *(s16x8*)(Bs + r * 32 + ak) = *(const s16x8*)(Bt + (size_t)(bcol + r) * K + k0 + ak);
    }
    __syncthreads();
    s16x8 af[4], bfr[4];
#pragma unroll
    for (int mi = 0; mi < 4; ++mi)
      af[mi] = *(const s16x8*)(As + (wr * 64 + mi * 16 + l15) * 32 + lg * 8);
#pragma unroll
    for (int ni = 0; ni < 4; ++ni)
      bfr[ni] = *(const s16x8*)(Bs + (wc * 64 + ni * 16 + l15) * 32 + lg * 8);
#pragma unroll
    for (int mi = 0; mi < 4; ++mi)
#pragma unroll
      for (int ni = 0; ni < 4; ++ni)
        acc[mi][ni] = __builtin_amdgcn_mfma_f32_16x16x32_bf16(af[mi], bfr[ni], acc[mi][ni], 0, 0, 0);
    __syncthreads();
  }

#pragma unroll
  for (int mi = 0; mi < 4; ++mi)
#pragma unroll
    for (int ni = 0; ni < 4; ++ni)
#pragma unroll
      for (int r = 0; r < 4; ++r) {
        int row = brow + wr * 64 + mi * 16 + lg * 4 + r;   // C/D: row=(lane>>4)*4+reg
        int col = bcol + wc * 64 + ni * 16 + l15;          //      col=lane&15
        float v = acc[mi][ni][r];
        if (MODE == 0) {
          v += bias[col];
          int b = row >> 11, s = row & 2047;
          int cc = col & 1023;
          int h = cc >> 6, e = cc & 63;
          bf16* dst = (col < 1024) ? o0 : o1;
          dst[((((size_t)b * NH + h) * NS) + s) * NHD + e] = __float2bfloat16(v);
        } else if (MODE == 1) {
          int b = row >> 11, s = row & 2047;
          int h = col >> 6, e = col & 63;
          o0[((((size_t)b * NH + h) * NS) + s) * NHD + e] = __float2bfloat16(v);
        } else {
          of[(size_t)row * N + col] = v;
        }
      }
}

// ---------------- fused causal shaped attention ----------------
// grid: (qt=S/64, H, B), block 256 (4 waves x 16 q-rows). kv tiles of 32.
__global__ __launch_bounds__(256) void attn_kernel(const bf16* __restrict__ qb,
                                                   const bf16* __restrict__ kb,
                                                   const bf16* __restrict__ vb,
                                                   const float* __restrict__ rg,
                                                   const float* __restrict__ sg,
                                                   const float* __restrict__ cg,
                                                   bf16* __restrict__ out) {
  const int qt = blockIdx.x, h = blockIdx.y, b = blockIdx.z;
  const int tid = threadIdx.x, wave = tid >> 6, lane = tid & 63;
  const int l15 = lane & 15, lg = lane >> 4;

  __shared__ alignas(16) bf16 Kt[32 * 64];       // [kv][hd]
  __shared__ alignas(16) bf16 Vt[64 * 32];       // [hd][kv] (transposed)
  __shared__ alignas(16) bf16 Pl[4][16 * 32];    // per-wave P
  __shared__ alignas(16) bf16 Pc[4][16 * 32];    // per-wave causal 0/1

  const size_t hoff = ((size_t)b * NH + h) * NS * NHD;
  const bf16* Q = qb + hoff;
  const bf16* Kg = kb + hoff;
  const bf16* Vg = vb + hoff;

  const int qbase = qt * 64 + wave * 16;
  // Q A-fragments (rows l15, k=lg*8..+8), hd split 0..31 / 32..63
  s16x8 qa0 = *(const s16x8*)(Q + (size_t)(qbase + l15) * NHD + lg * 8);
  s16x8 qa1 = *(const s16x8*)(Q + (size_t)(qbase + l15) * NHD + 32 + lg * 8);

  f32x4 acc_o[4] = {};
  f32x4 acc_c[4] = {};
  float m_run[4], l_run[4];
#pragma unroll
  for (int r = 0; r < 4; ++r) { m_run[r] = -INFINITY; l_run[r] = 0.f; }

  const int ld_row = tid >> 3;       // 0..31
  const int ld_ke = (tid & 7) * 8;   // 0..56
  const bf16 one = __float2bfloat16(1.0f);
  const bf16 zero = __float2bfloat16(0.0f);

  const int ntiles = qt * 2 + 2;
  for (int t = 0; t < ntiles; ++t) {
    // stage K row-major, V transposed
    s16x8 kvld = *(const s16x8*)(Kg + ((size_t)t * 32 + ld_row) * NHD + ld_ke);
    *(s16x8*)(Kt + ld_row * 64 + ld_ke) = kvld;
    s16x8 vld = *(const s16x8*)(Vg + ((size_t)t * 32 + ld_row) * NHD + ld_ke);
    {
      unsigned short* vp = (unsigned short*)&vld;
      unsigned short* vt = (unsigned short*)Vt;
#pragma unroll
      for (int j = 0; j < 8; ++j) vt[(ld_ke + j) * 32 + ld_row] = vp[j];
    }
    __syncthreads();

    // scores: two 16-col subtiles, K-dim = HD = 64 -> 2 MFMAs each
    f32x4 s0 = {}, s1 = {};
    s16x8 kf;
    kf = *(const s16x8*)(Kt + (0 + l15) * 64 + lg * 8);
    s0 = __builtin_amdgcn_mfma_f32_16x16x32_bf16(qa0, kf, s0, 0, 0, 0);
    kf = *(const s16x8*)(Kt + (0 + l15) * 64 + 32 + lg * 8);
    s0 = __builtin_amdgcn_mfma_f32_16x16x32_bf16(qa1, kf, s0, 0, 0, 0);
    kf = *(const s16x8*)(Kt + (16 + l15) * 64 + lg * 8);
    s1 = __builtin_amdgcn_mfma_f32_16x16x32_bf16(qa0, kf, s1, 0, 0, 0);
    kf = *(const s16x8*)(Kt + (16 + l15) * 64 + 32 + lg * 8);
    s1 = __builtin_amdgcn_mfma_f32_16x16x32_bf16(qa1, kf, s1, 0, 0, 0);

    const int c0 = t * 32 + l15, c1 = t * 32 + 16 + l15;
    float corr_a[4];
#pragma unroll
    for (int r = 0; r < 4; ++r) {
      int srow = qbase + lg * 4 + r;
      float sA = (c0 <= srow) ? s0[r] * 0.125f : -INFINITY;
      float sB = (c1 <= srow) ? s1[r] * 0.125f : -INFINITY;
      float mx = fmaxf(sA, sB);
#pragma unroll
      for (int o = 1; o < 16; o <<= 1) mx = fmaxf(mx, __shfl_xor(mx, o, 64));
      float m_new = fmaxf(m_run[r], mx);
      corr_a[r] = __expf(m_run[r] - m_new);   // exp(-inf)=0 at first tile
      float pA = __expf(sA - m_new);
      float pB = __expf(sB - m_new);
      float rs = pA + pB;
#pragma unroll
      for (int o = 1; o < 16; o <<= 1) rs += __shfl_xor(rs, o, 64);
      l_run[r] = l_run[r] * corr_a[r] + rs;
      m_run[r] = m_new;
      int prow = lg * 4 + r;
      Pl[wave][prow * 32 + l15] = __float2bfloat16(pA);
      Pl[wave][prow * 32 + 16 + l15] = __float2bfloat16(pB);
      Pc[wave][prow * 32 + l15] = (c0 <= srow) ? one : zero;
      Pc[wave][prow * 32 + 16 + l15] = (c1 <= srow) ? one : zero;
    }
    // rescale running O
#pragma unroll
    for (int sub = 0; sub < 4; ++sub)
#pragma unroll
      for (int r = 0; r < 4; ++r) acc_o[sub][r] *= corr_a[r];

    // PV + causal-ones V (prefix sum), K-dim = 32 kv
    s16x8 pa = *(const s16x8*)(Pl[wave] + l15 * 32 + lg * 8);
    s16x8 pc = *(const s16x8*)(Pc[wave] + l15 * 32 + lg * 8);
#pragma unroll
    for (int sub = 0; sub < 4; ++sub) {
      s16x8 vf = *(const s16x8*)(Vt + (sub * 16 + l15) * 32 + lg * 8);
      acc_o[sub] = __builtin_amdgcn_mfma_f32_16x16x32_bf16(pa, vf, acc_o[sub], 0, 0, 0);
      acc_c[sub] = __builtin_amdgcn_mfma_f32_16x16x32_bf16(pc, vf, acc_c[sub], 0, 0, 0);
    }
    __syncthreads();
  }

  // epilogue: rg*softmaxPV + sg*v_row - cg*prefix/(row+1), write [B,S,D] bf16
  const float rgh = rg[h], sgh = sg[h], cgh = cg[h];
#pragma unroll
  for (int sub = 0; sub < 4; ++sub)
#pragma unroll
    for (int r = 0; r < 4; ++r) {
      int srow = qbase + lg * 4 + r;
      int hd = sub * 16 + l15;
      float vrow = __bfloat162float(Vg[(size_t)srow * NHD + hd]);
      float val = rgh * (acc_o[sub][r] / l_run[r]) + sgh * vrow -
                  cgh * (acc_c[sub][r] / (float)(srow + 1));
      out[((size_t)b * NS + srow) * ND + h * NHD + hd] = __float2bfloat16(val);
    }
}

extern "C" void kernel_launch(void* const* d_in, const int* in_sizes, int n_in,
                              void* d_out, int out_size, void* d_ws, size_t ws_size,
                              hipStream_t stream) {
  const float* x = (const float*)d_in[0];
  const float* qk_w = (const float*)d_in[1];
  const float* qk_b = (const float*)d_in[2];
  const float* v_w = (const float*)d_in[3];
  const float* cproj_w = (const float*)d_in[4];
  const float* rg = (const float*)d_in[5];
  const float* sg = (const float*)d_in[6];
  const float* cg = (const float*)d_in[7];
  float* out = (float*)d_out;

  char* p = (char*)d_ws;
  bf16* xb = (bf16*)p;   p += (size_t)4096 * 1024 * 2;   // x bf16 [B*S, D]
  bf16* qkwt = (bf16*)p; p += (size_t)2048 * 1024 * 2;   // qk_w^T bf16 [2D, D]
  bf16* vwt = (bf16*)p;  p += (size_t)1024 * 1024 * 2;   // v_w^T
  bf16* cpwt = (bf16*)p; p += (size_t)1024 * 1024 * 2;   // cproj_w^T
  bf16* qbuf = (bf16*)p; p += (size_t)NB * NH * NS * NHD * 2;
  bf16* kbuf = (bf16*)p; p += (size_t)NB * NH * NS * NHD * 2;
  bf16* vbuf = (bf16*)p; p += (size_t)NB * NH * NS * NHD * 2;
  bf16* aout = (bf16*)p; p += (size_t)4096 * 1024 * 2;   // attn out [B,S,D]

  cvt_bf16<<<4096, 256, 0, stream>>>(x, xb, (NB * NS * ND) / 4);
  tconv<<<dim3(64, 32), dim3(32, 8), 0, stream>>>(qk_w, qkwt, 1024, 2048);
  tconv<<<dim3(32, 32), dim3(32, 8), 0, stream>>>(v_w, vwt, 1024, 1024);
  tconv<<<dim3(32, 32), dim3(32, 8), 0, stream>>>(cproj_w, cpwt, 1024, 1024);

  gemm_bt<0><<<dim3(16, 32), 256, 0, stream>>>(xb, qkwt, qk_b, qbuf, kbuf, nullptr, 4096, 2048, 1024);
  gemm_bt<1><<<dim3(8, 32), 256, 0, stream>>>(xb, vwt, nullptr, vbuf, nullptr, nullptr, 4096, 1024, 1024);
  attn_kernel<<<dim3(NS / 64, NH, NB), 256, 0, stream>>>(qbuf, kbuf, vbuf, rg, sg, cg, aout);
  gemm_bt<2><<<dim3(8, 32), 256, 0, stream>>>(aout, cpwt, nullptr, nullptr, nullptr, out, 4096, 1024, 1024);
}

// Round 2
// 180.118 us; speedup vs baseline: 1.8959x; 1.8959x over previous
//
#include <hip/hip_runtime.h>
#include <hip/hip_bf16.h>

// Problem: B=2, S=2048, D=1024, H=16, HD=64
// out[i] = rg*(softmax(QK^T/8, causal) @ V)[i] + sg*V[i] - cg*prefixsum(V)[i]/(i+1), then @cproj_w

typedef __hip_bfloat16 bf16;
typedef short s16x8 __attribute__((ext_vector_type(8)));
typedef short s16x4 __attribute__((ext_vector_type(4)));
typedef float f32x4 __attribute__((ext_vector_type(4)));

#define NB 2
#define NS 2048
#define ND 1024
#define NH 16
#define NHD 64

// byte-level XOR swizzle for 128B-row LDS tiles: spreads 16B blocks across banks
#define SWZB(r) (((((r) >> 3) ^ (r)) & 7) << 4)

__device__ __forceinline__ float b2f(unsigned short u) {
  union { float f; unsigned int i; } c; c.i = ((unsigned int)u) << 16; return c.f;
}

// ---------------- f32 -> bf16 conversion (vectorized) ----------------
__global__ __launch_bounds__(256) void cvt_bf16(const float* __restrict__ in,
                                                bf16* __restrict__ out, int n4) {
  int i = blockIdx.x * 256 + threadIdx.x;
  if (i >= n4) return;
  float4 v = ((const float4*)in)[i];
  ushort4 o;
  bf16 t;
  t = __float2bfloat16(v.x); __builtin_memcpy(&o.x, &t, 2);
  t = __float2bfloat16(v.y); __builtin_memcpy(&o.y, &t, 2);
  t = __float2bfloat16(v.z); __builtin_memcpy(&o.z, &t, 2);
  t = __float2bfloat16(v.w); __builtin_memcpy(&o.w, &t, 2);
  ((ushort4*)out)[i] = o;
}

// ------------- transpose + convert: in[K,N] f32 -> out[N,K] bf16 -------------
__global__ __launch_bounds__(256) void tconv(const float* __restrict__ in,
                                             bf16* __restrict__ out, int K, int N) {
  __shared__ float tile[32][33];
  int nt = blockIdx.x * 32, kt = blockIdx.y * 32;
  int tx = threadIdx.x, ty = threadIdx.y;  // block (32,8)
#pragma unroll
  for (int j = 0; j < 32; j += 8)
    tile[ty + j][tx] = in[(size_t)(kt + ty + j) * N + nt + tx];
  __syncthreads();
#pragma unroll
  for (int j = 0; j < 32; j += 8)
    out[(size_t)(nt + ty + j) * K + kt + tx] = __float2bfloat16(tile[tx][ty + j]);
}

// ---------------- 128x128x32 bf16 MFMA GEMM, B^T input ----------------
// MODE 0: C = A@B + bias -> split cols [0,1024)->q, [1024,2048)->k, head-major bf16
// MODE 1: C = A@B -> v head-major bf16
// MODE 2: C = A@B -> f32 row-major (d_out)
template <int MODE>
__global__ __launch_bounds__(256) void gemm_bt(const bf16* __restrict__ A,
                                               const bf16* __restrict__ Bt,
                                               const float* __restrict__ bias,
                                               bf16* __restrict__ o0, bf16* __restrict__ o1,
                                               float* __restrict__ of,
                                               int M, int N, int K) {
  __shared__ alignas(16) bf16 As[128 * 32];
  __shared__ alignas(16) bf16 Bs[128 * 32];
  const int tid = threadIdx.x;
  const int wave = tid >> 6, lane = tid & 63;
  const int l15 = lane & 15, lg = lane >> 4;
  const int wr = wave >> 1, wc = wave & 1;
  const int brow = blockIdx.y * 128, bcol = blockIdx.x * 128;

  f32x4 acc[4][4] = {};
  const int arow = tid >> 2;        // 0..63
  const int ak = (tid & 3) * 8;     // 0,8,16,24

  for (int k0 = 0; k0 < K; k0 += 32) {
#pragma unroll
    for (int c = 0; c < 2; ++c) {
      int r = arow + c * 64;
      *(s16x8*)(As + r * 32 + ak) = *(const s16x8*)(A + (size_t)(brow + r) * K + k0 + ak);
      *(s16x8*)(Bs + r * 32 + ak) = *(const s16x8*)(Bt + (size_t)(bcol + r) * K + k0 + ak);
    }
    __syncthreads();
    s16x8 af[4], bfr[4];
#pragma unroll
    for (int mi = 0; mi < 4; ++mi)
      af[mi] = *(const s16x8*)(As + (wr * 64 + mi * 16 + l15) * 32 + lg * 8);
#pragma unroll
    for (int ni = 0; ni < 4; ++ni)
      bfr[ni] = *(const s16x8*)(Bs + (wc * 64 + ni * 16 + l15) * 32 + lg * 8);
#pragma unroll
    for (int mi = 0; mi < 4; ++mi)
#pragma unroll
      for (int ni = 0; ni < 4; ++ni)
        acc[mi][ni] = __builtin_amdgcn_mfma_f32_16x16x32_bf16(af[mi], bfr[ni], acc[mi][ni], 0, 0, 0);
    __syncthreads();
  }

#pragma unroll
  for (int mi = 0; mi < 4; ++mi)
#pragma unroll
    for (int ni = 0; ni < 4; ++ni)
#pragma unroll
      for (int r = 0; r < 4; ++r) {
        int row = brow + wr * 64 + mi * 16 + lg * 4 + r;   // C/D: row=(lane>>4)*4+reg
        int col = bcol + wc * 64 + ni * 16 + l15;          //      col=lane&15
        float v = acc[mi][ni][r];
        if (MODE == 0) {
          v += bias[col];
          int b = row >> 11, s = row & 2047;
          int cc = col & 1023;
          int h = cc >> 6, e = cc & 63;
          bf16* dst = (col < 1024) ? o0 : o1;
          dst[((((size_t)b * NH + h) * NS) + s) * NHD + e] = __float2bfloat16(v);
        } else if (MODE == 1) {
          int b = row >> 11, s = row & 2047;
          int h = col >> 6, e = col & 63;
          o0[((((size_t)b * NH + h) * NS) + s) * NHD + e] = __float2bfloat16(v);
        } else {
          of[(size_t)row * N + col] = v;
        }
      }
}

// ---------------- fused causal shaped attention ----------------
// grid: (16, H, B). Block j handles q-tile pair {j, 31-j} (33 kv-tiles each,
// perfectly balanced). 4 waves x 16 q-rows, KVBLK=64, swizzled LDS.
__global__ __launch_bounds__(256, 2) void attn_kernel(const bf16* __restrict__ qb,
                                                      const bf16* __restrict__ kb,
                                                      const bf16* __restrict__ vb,
                                                      const float* __restrict__ rg,
                                                      const float* __restrict__ sg,
                                                      const float* __restrict__ cg,
                                                      bf16* __restrict__ out) {
  const int h = blockIdx.y, b = blockIdx.z;
  const int tid = threadIdx.x, wave = tid >> 6, lane = tid & 63;
  const int l15 = lane & 15, lg = lane >> 4;

  __shared__ alignas(16) char Kt[64 * 128];      // K tile [kv][hd], swizzled
  __shared__ alignas(16) char Vt[64 * 128];      // V^T tile [hd][kv], swizzled
  __shared__ alignas(16) char Pl[4][16 * 128];   // per-wave P, swizzled
  __shared__ alignas(16) char Pc[4][16 * 128];   // per-wave causal mask (diag tile only)

  const size_t hoff = ((size_t)b * NH + h) * NS * NHD;
  const bf16* Q = qb + hoff;
  const bf16* Kg = kb + hoff;
  const bf16* Vg = vb + hoff;
  const float rgh = rg[h], sgh = sg[h], cgh = cg[h];

  char* Plw = Pl[wave];
  char* Pcw = Pc[wave];

  const int krow = tid >> 2;          // 0..63 (staging row)
  const int kce = (tid & 3) * 16;     // staging col element offset
  const short ONE = 0x3F80;           // bf16 1.0
  const s16x8 ones = {ONE, ONE, ONE, ONE, ONE, ONE, ONE, ONE};
  const bf16 one_bf = __float2bfloat16(1.0f);
  const bf16 zero_bf = __float2bfloat16(0.0f);

  for (int pass = 0; pass < 2; ++pass) {
    const int qt = pass ? (31 - (int)blockIdx.x) : (int)blockIdx.x;
    const int qbase = qt * 64 + wave * 16;

    s16x8 qa0 = *(const s16x8*)(Q + (size_t)(qbase + l15) * NHD + lg * 8);
    s16x8 qa1 = *(const s16x8*)(Q + (size_t)(qbase + l15) * NHD + 32 + lg * 8);

    f32x4 acc_o[4] = {};
    f32x4 acc_c[4] = {};
    float m_run[4] = {-INFINITY, -INFINITY, -INFINITY, -INFINITY};
    float l_run[4] = {0.f, 0.f, 0.f, 0.f};

    // prefetch tile 0 into registers
    const bf16* ks = Kg + (size_t)krow * NHD + kce;
    const bf16* vs = Vg + (size_t)krow * NHD + kce;
    s16x8 kr0 = *(const s16x8*)ks, kr1 = *(const s16x8*)(ks + 8);
    s16x8 vr0 = *(const s16x8*)vs, vr1 = *(const s16x8*)(vs + 8);

    for (int t = 0; t <= qt; ++t) {
      __syncthreads();                 // previous tile fully consumed
      // K tile: 2 swizzled b128 writes
      *(s16x8*)(Kt + krow * 128 + ((kce * 2) ^ SWZB(krow))) = kr0;
      *(s16x8*)(Kt + krow * 128 + ((kce * 2 + 16) ^ SWZB(krow))) = kr1;
      // V^T tile: 16 swizzled b16 writes
      {
        const unsigned short* vp0 = (const unsigned short*)&vr0;
        const unsigned short* vp1 = (const unsigned short*)&vr1;
#pragma unroll
        for (int j = 0; j < 8; ++j) {
          int d0 = kce + j, d1 = kce + 8 + j;
          *(unsigned short*)(Vt + d0 * 128 + ((krow * 2) ^ SWZB(d0))) = vp0[j];
          *(unsigned short*)(Vt + d1 * 128 + ((krow * 2) ^ SWZB(d1))) = vp1[j];
        }
      }
      // prefetch next tile (loads stay in flight across barrier/compute)
      if (t < qt) {
        const bf16* ks2 = Kg + ((size_t)(t + 1) * 64 + krow) * NHD + kce;
        const bf16* vs2 = Vg + ((size_t)(t + 1) * 64 + krow) * NHD + kce;
        kr0 = *(const s16x8*)ks2; kr1 = *(const s16x8*)(ks2 + 8);
        vr0 = *(const s16x8*)vs2; vr1 = *(const s16x8*)(vs2 + 8);
      }
      __syncthreads();                 // tile ready

      // ---- QK^T: 4 col-subtiles x K=64 ----
      f32x4 sc[4] = {};
#pragma unroll
      for (int c = 0; c < 4; ++c) {
        int row = c * 16 + l15;
        s16x8 kf0 = *(const s16x8*)(Kt + row * 128 + ((lg * 16) ^ SWZB(row)));
        s16x8 kf1 = *(const s16x8*)(Kt + row * 128 + ((lg * 16 + 64) ^ SWZB(row)));
        sc[c] = __builtin_amdgcn_mfma_f32_16x16x32_bf16(qa0, kf0, sc[c], 0, 0, 0);
        sc[c] = __builtin_amdgcn_mfma_f32_16x16x32_bf16(qa1, kf1, sc[c], 0, 0, 0);
      }

      const bool diag = (t == qt);
      float corr[4];
#pragma unroll
      for (int r = 0; r < 4; ++r) {
        const int srt = wave * 16 + lg * 4 + r;  // row within tile
        float x0 = sc[0][r] * 0.125f, x1 = sc[1][r] * 0.125f;
        float x2 = sc[2][r] * 0.125f, x3 = sc[3][r] * 0.125f;
        if (diag) {
          x0 = (0 + l15 <= srt) ? x0 : -INFINITY;
          x1 = (16 + l15 <= srt) ? x1 : -INFINITY;
          x2 = (32 + l15 <= srt) ? x2 : -INFINITY;
          x3 = (48 + l15 <= srt) ? x3 : -INFINITY;
        }
        float mx = fmaxf(fmaxf(x0, x1), fmaxf(x2, x3));
#pragma unroll
        for (int o = 1; o < 16; o <<= 1) mx = fmaxf(mx, __shfl_xor(mx, o, 64));
        float m_new = fmaxf(m_run[r], mx);
        float cr = __expf(m_run[r] - m_new);     // exp(-inf)=0 at first tile
        float p0 = __expf(x0 - m_new), p1 = __expf(x1 - m_new);
        float p2 = __expf(x2 - m_new), p3 = __expf(x3 - m_new);
        float rs = (p0 + p1) + (p2 + p3);
#pragma unroll
        for (int o = 1; o < 16; o <<= 1) rs += __shfl_xor(rs, o, 64);
        l_run[r] = l_run[r] * cr + rs;
        m_run[r] = m_new;
        corr[r] = cr;
        const int prow = lg * 4 + r;
        char* plr = Plw + prow * 128;
        const int sw = SWZB(prow);
        *(bf16*)(plr + (((0 + l15) * 2) ^ sw)) = __float2bfloat16(p0);
        *(bf16*)(plr + (((16 + l15) * 2) ^ sw)) = __float2bfloat16(p1);
        *(bf16*)(plr + (((32 + l15) * 2) ^ sw)) = __float2bfloat16(p2);
        *(bf16*)(plr + (((48 + l15) * 2) ^ sw)) = __float2bfloat16(p3);
        if (diag) {
          char* pcr = Pcw + prow * 128;
          *(bf16*)(pcr + (((0 + l15) * 2) ^ sw)) = (0 + l15 <= srt) ? one_bf : zero_bf;
          *(bf16*)(pcr + (((16 + l15) * 2) ^ sw)) = (16 + l15 <= srt) ? one_bf : zero_bf;
          *(bf16*)(pcr + (((32 + l15) * 2) ^ sw)) = (32 + l15 <= srt) ? one_bf : zero_bf;
          *(bf16*)(pcr + (((48 + l15) * 2) ^ sw)) = (48 + l15 <= srt) ? one_bf : zero_bf;
        }
      }
      // rescale running O (prefix acc_c is NOT rescaled)
#pragma unroll
      for (int sub = 0; sub < 4; ++sub)
#pragma unroll
        for (int r = 0; r < 4; ++r) acc_o[sub][r] *= corr[r];

      // ---- PV + prefix-V ----
      s16x8 pa0 = *(const s16x8*)(Plw + l15 * 128 + ((lg * 16) ^ SWZB(l15)));
      s16x8 pa1 = *(const s16x8*)(Plw + l15 * 128 + ((lg * 16 + 64) ^ SWZB(l15)));
      s16x8 pc0 = ones, pc1 = ones;
      if (diag) {
        pc0 = *(const s16x8*)(Pcw + l15 * 128 + ((lg * 16) ^ SWZB(l15)));
        pc1 = *(const s16x8*)(Pcw + l15 * 128 + ((lg * 16 + 64) ^ SWZB(l15)));
      }
#pragma unroll
      for (int sub = 0; sub < 4; ++sub) {
        int vrow = sub * 16 + l15;
        s16x8 vf0 = *(const s16x8*)(Vt + vrow * 128 + ((lg * 16) ^ SWZB(vrow)));
        s16x8 vf1 = *(const s16x8*)(Vt + vrow * 128 + ((lg * 16 + 64) ^ SWZB(vrow)));
        acc_o[sub] = __builtin_amdgcn_mfma_f32_16x16x32_bf16(pa0, vf0, acc_o[sub], 0, 0, 0);
        acc_o[sub] = __builtin_amdgcn_mfma_f32_16x16x32_bf16(pa1, vf1, acc_o[sub], 0, 0, 0);
        acc_c[sub] = __builtin_amdgcn_mfma_f32_16x16x32_bf16(pc0, vf0, acc_c[sub], 0, 0, 0);
        acc_c[sub] = __builtin_amdgcn_mfma_f32_16x16x32_bf16(pc1, vf1, acc_c[sub], 0, 0, 0);
      }
    }

    // epilogue: V rows for the skip term are still in the diagonal LDS tile
#pragma unroll
    for (int sub = 0; sub < 4; ++sub) {
      const int hd = sub * 16 + l15;
      const int cb = (wave * 16 + lg * 4) * 2;  // byte col of row qbase+lg*4 within tile
      s16x4 vr4 = *(const s16x4*)(Vt + hd * 128 + (cb ^ SWZB(hd)));
      const unsigned short* vbits = (const unsigned short*)&vr4;
#pragma unroll
      for (int r = 0; r < 4; ++r) {
        int srow = qbase + lg * 4 + r;
        float vrow = b2f(vbits[r]);
        float val = rgh * (acc_o[sub][r] / l_run[r]) + sgh * vrow -
                    cgh * (acc_c[sub][r] / (float)(srow + 1));
        out[((size_t)b * NS + srow) * ND + h * NHD + hd] = __float2bfloat16(val);
      }
    }
  }
}

extern "C" void kernel_launch(void* const* d_in, const int* in_sizes, int n_in,
                              void* d_out, int out_size, void* d_ws, size_t ws_size,
                              hipStream_t stream) {
  const float* x = (const float*)d_in[0];
  const float* qk_w = (const float*)d_in[1];
  const float* qk_b = (const float*)d_in[2];
  const float* v_w = (const float*)d_in[3];
  const float* cproj_w = (const float*)d_in[4];
  const float* rg = (const float*)d_in[5];
  const float* sg = (const float*)d_in[6];
  const float* cg = (const float*)d_in[7];
  float* out = (float*)d_out;

  char* p = (char*)d_ws;
  bf16* xb = (bf16*)p;   p += (size_t)4096 * 1024 * 2;   // x bf16 [B*S, D]
  bf16* qkwt = (bf16*)p; p += (size_t)2048 * 1024 * 2;   // qk_w^T bf16 [2D, D]
  bf16* vwt = (bf16*)p;  p += (size_t)1024 * 1024 * 2;   // v_w^T
  bf16* cpwt = (bf16*)p; p += (size_t)1024 * 1024 * 2;   // cproj_w^T
  bf16* qbuf = (bf16*)p; p += (size_t)NB * NH * NS * NHD * 2;
  bf16* kbuf = (bf16*)p; p += (size_t)NB * NH * NS * NHD * 2;
  bf16* vbuf = (bf16*)p; p += (size_t)NB * NH * NS * NHD * 2;
  bf16* aout = (bf16*)p; p += (size_t)4096 * 1024 * 2;   // attn out [B,S,D]

  cvt_bf16<<<4096, 256, 0, stream>>>(x, xb, (NB * NS * ND) / 4);
  tconv<<<dim3(64, 32), dim3(32, 8), 0, stream>>>(qk_w, qkwt, 1024, 2048);
  tconv<<<dim3(32, 32), dim3(32, 8), 0, stream>>>(v_w, vwt, 1024, 1024);
  tconv<<<dim3(32, 32), dim3(32, 8), 0, stream>>>(cproj_w, cpwt, 1024, 1024);

  gemm_bt<0><<<dim3(16, 32), 256, 0, stream>>>(xb, qkwt, qk_b, qbuf, kbuf, nullptr, 4096, 2048, 1024);
  gemm_bt<1><<<dim3(8, 32), 256, 0, stream>>>(xb, vwt, nullptr, vbuf, nullptr, nullptr, 4096, 1024, 1024);
  attn_kernel<<<dim3(16, NH, NB), 256, 0, stream>>>(qbuf, kbuf, vbuf, rg, sg, cg, aout);
  gemm_bt<2><<<dim3(8, 32), 256, 0, stream>>>(aout, cpwt, nullptr, nullptr, nullptr, out, 4096, 1024, 1024);
}